// Round 7
// baseline (229.167 us; speedup 1.0000x reference)
//
#include <hip/hip_runtime.h>

typedef __attribute__((ext_vector_type(8))) short bf16x8;
typedef __attribute__((ext_vector_type(4))) float f32x4;

#define LPAD 2432
#define LKV  2382
#define NSEQ 2304
#define CDIM 512

__device__ __forceinline__ unsigned short f2bf(float f) {
  unsigned int u = __builtin_bit_cast(unsigned int, f);
  u += 0x7fffu + ((u >> 16) & 1u);
  return (unsigned short)(u >> 16);
}
__device__ __forceinline__ float bf2f(unsigned short s) {
  unsigned int u = ((unsigned int)s) << 16;
  return __builtin_bit_cast(float, u);
}
__device__ __forceinline__ f32x4 MFMA(bf16x8 a, bf16x8 b, f32x4 c) {
  return __builtin_amdgcn_mfma_f32_16x16x32_bf16(a, b, c, 0, 0, 0);
}
__device__ __forceinline__ void stage16(const unsigned short* g, unsigned short* l) {
  __builtin_amdgcn_global_load_lds((const __attribute__((address_space(1))) void*)g,
                                   (__attribute__((address_space(3))) void*)l, 16, 0, 0);
}
__device__ __forceinline__ unsigned int cvtpk(float a, float b) {
  unsigned int r;
  asm("v_cvt_pk_bf16_f32 %0, %1, %2" : "=v"(r) : "v"(a), "v"(b));
  return r;
}

// ---------------- weight transpose + bf16 convert ----------------
__global__ void k_prep(const float* __restrict__ Wq, const float* __restrict__ Wkv,
                       const float* __restrict__ Wctx, const float* __restrict__ Wout,
                       unsigned short* __restrict__ WqT, unsigned short* __restrict__ WkvT,
                       unsigned short* __restrict__ WctxT, unsigned short* __restrict__ WoutT) {
  int idx = blockIdx.x * 256 + threadIdx.x;
  if (idx < 262144) {
    int n = idx >> 9, k = idx & 511;
    WqT[idx] = f2bf(Wq[k * 512 + n]);
  } else if ((idx -= 262144) < 65536) {
    int n = idx >> 9, k = idx & 511;
    WkvT[idx] = f2bf(Wkv[k * 128 + n]);
  } else if ((idx -= 65536) < 98304) {
    int n = idx / 768, k = idx - n * 768;
    WctxT[idx] = f2bf(Wctx[k * 128 + n]);
  } else {
    idx -= 98304;
    int n = idx >> 9, k = idx & 511;
    WoutT[idx] = f2bf(Wout[k * 512 + n]);
  }
}

// ---------------- LN over C of x (B,C,N) -> xn bf16 (B*N, C) ----------------
__global__ void k_ln1(const float* __restrict__ x, const float* __restrict__ g,
                      unsigned short* __restrict__ xn) {
  int b = blockIdx.y;
  int i0 = blockIdx.x * 32;
  int t = threadIdx.x;
  int ii = t & 31, ci = t >> 5;
  const float* xb = x + (size_t)b * CDIM * NSEQ;
  float s = 0.f, s2 = 0.f;
  for (int c = ci; c < CDIM; c += 8) {
    float v = xb[(size_t)c * NSEQ + i0 + ii];
    s += v; s2 += v * v;
  }
  __shared__ float ls[8][32], ls2[8][32];
  __shared__ float lmu[32], lrs[32];
  ls[ci][ii] = s; ls2[ci][ii] = s2;
  __syncthreads();
  if (t < 32) {
    float a = 0.f, a2 = 0.f;
    for (int q = 0; q < 8; q++) { a += ls[q][t]; a2 += ls2[q][t]; }
    float mu = a * (1.0f / 512.0f);
    float var = a2 * (1.0f / 512.0f) - mu * mu;
    lmu[t] = mu; lrs[t] = rsqrtf(var + 1e-5f);
  }
  __syncthreads();
  float mu = lmu[ii], rs = lrs[ii];
  unsigned short* xrow = xn + (size_t)(b * NSEQ + i0 + ii) * CDIM;
  for (int c = ci; c < CDIM; c += 8) {
    float v = xb[(size_t)c * NSEQ + i0 + ii];
    xrow[c] = f2bf((v - mu) * rs * g[c]);
  }
}

// ---------------- context LN + projection; null row + zero pads ----------
__global__ void k_ctx(const float* __restrict__ ctx, const float* __restrict__ g,
                      const float* __restrict__ be, const unsigned short* __restrict__ WctxT,
                      const float* __restrict__ bctx, const float* __restrict__ null_kv,
                      unsigned short* __restrict__ kb, unsigned short* __restrict__ vt) {
  int b = blockIdx.y, j = blockIdx.x;
  int t = threadIdx.x;
  if (j == 77) {
    if (t < 64) kb[((size_t)b * LPAD + 77) * 64 + t] = f2bf(null_kv[t]);
    else vt[((size_t)b * 64 + (t - 64)) * LPAD + 77] = f2bf(null_kv[64 + (t - 64)]);
    return;
  }
  if (j > 77) {
    int jj = LKV + (j - 78);
    if (t < 64) kb[((size_t)b * LPAD + jj) * 64 + t] = 0;
    else vt[((size_t)b * 64 + (t - 64)) * LPAD + jj] = 0;
    return;
  }
  __shared__ float row[768];
  __shared__ float red[4];
  const float* src = ctx + (size_t)(b * 77 + j) * 768;
  float s = 0.f, s2 = 0.f;
  for (int k = t; k < 768; k += 128) {
    float v = src[k];
    row[k] = v; s += v; s2 += v * v;
  }
  for (int o = 32; o; o >>= 1) { s += __shfl_xor(s, o); s2 += __shfl_xor(s2, o); }
  if ((t & 63) == 0) { red[(t >> 6) * 2] = s; red[(t >> 6) * 2 + 1] = s2; }
  __syncthreads();
  float S = red[0] + red[2], S2 = red[1] + red[3];
  float mu = S * (1.0f / 768.0f);
  float rs = rsqrtf(S2 * (1.0f / 768.0f) - mu * mu + 1e-5f);
  __syncthreads();
  for (int k = t; k < 768; k += 128) row[k] = (row[k] - mu) * rs * g[k] + be[k];
  __syncthreads();
  const uint4* w4 = reinterpret_cast<const uint4*>(WctxT + (size_t)t * 768);
  float acc = 0.f;
  for (int k8 = 0; k8 < 96; k8++) {
    union { uint4 u; unsigned short s[8]; } wv;
    wv.u = w4[k8];
#pragma unroll
    for (int e = 0; e < 8; e++) acc += row[k8 * 8 + e] * bf2f(wv.s[e]);
  }
  acc += bctx[t];
  if (t < 64) kb[((size_t)b * LPAD + j) * 64 + t] = f2bf(acc);
  else vt[((size_t)b * 64 + (t - 64)) * LPAD + j] = f2bf(acc);
}

// ---------------- MFMA GEMM ----------------
template <int MODE>
__global__ __launch_bounds__(256, 1) void k_gemm(
    const unsigned short* __restrict__ A, const unsigned short* __restrict__ BT0,
    const unsigned short* __restrict__ BT1, unsigned short* __restrict__ out_q,
    unsigned short* __restrict__ out_k, unsigned short* __restrict__ out_vt,
    float* __restrict__ out_proj) {
  int m0 = blockIdx.x * 128, n0 = blockIdx.y * 128;
  int t = threadIdx.x;
  int lane = t & 63, w = t >> 6;
  int wm = w >> 1, wn = w & 1;
  int G = lane >> 4, li = lane & 15;
  __shared__ unsigned short Al[128][72];
  __shared__ unsigned short Bl[128][72];
  const unsigned short* BT = (MODE == 0 && n0 >= 512) ? BT1 : BT0;
  int bn0 = (MODE == 0 && n0 >= 512) ? n0 - 512 : n0;
  f32x4 zero = {0.f, 0.f, 0.f, 0.f};
  f32x4 acc[4][4];
#pragma unroll
  for (int a = 0; a < 4; a++)
#pragma unroll
    for (int c = 0; c < 4; c++) acc[a][c] = zero;
  int sr = t >> 1, sc = (t & 1) * 32;
  for (int k0 = 0; k0 < 512; k0 += 64) {
    const uint4* sA = reinterpret_cast<const uint4*>(A + (size_t)(m0 + sr) * 512 + k0 + sc);
    const uint4* sB = reinterpret_cast<const uint4*>(BT + (size_t)(bn0 + sr) * 512 + k0 + sc);
    uint4 a0 = sA[0], a1 = sA[1], a2 = sA[2], a3 = sA[3];
    uint4 b0 = sB[0], b1 = sB[1], b2 = sB[2], b3 = sB[3];
    uint4* dA = reinterpret_cast<uint4*>(&Al[sr][sc]);
    uint4* dB = reinterpret_cast<uint4*>(&Bl[sr][sc]);
    dA[0] = a0; dA[1] = a1; dA[2] = a2; dA[3] = a3;
    dB[0] = b0; dB[1] = b1; dB[2] = b2; dB[3] = b3;
    __syncthreads();
#pragma unroll
    for (int ks = 0; ks < 2; ks++) {
      bf16x8 af[4], bfr[4];
#pragma unroll
      for (int f = 0; f < 4; f++) {
        af[f] = *reinterpret_cast<const bf16x8*>(&Al[wm * 64 + f * 16 + li][ks * 32 + G * 8]);
        bfr[f] = *reinterpret_cast<const bf16x8*>(&Bl[wn * 64 + f * 16 + li][ks * 32 + G * 8]);
      }
#pragma unroll
      for (int fm = 0; fm < 4; fm++)
#pragma unroll
        for (int fn = 0; fn < 4; fn++)
          acc[fm][fn] = MFMA(af[fm], bfr[fn], acc[fm][fn]);
    }
    __syncthreads();
  }
#pragma unroll
  for (int fm = 0; fm < 4; fm++)
#pragma unroll
    for (int fn = 0; fn < 4; fn++)
#pragma unroll
      for (int r = 0; r < 4; r++) {
        int row = m0 + wm * 64 + fm * 16 + G * 4 + r;
        int col = n0 + wn * 64 + fn * 16 + li;
        float v = acc[fm][fn][r];
        if (MODE == 0) {
          int b = row / NSEQ, i = row - b * NSEQ;
          // q pre-scaled by 1/sqrt(dh) * log2(e): softmax runs in exp2 domain
          if (col < 512) out_q[(size_t)row * 512 + col] = f2bf(v * 0.18033688011112042f);
          else if (col < 576) out_k[((size_t)b * LPAD + 78 + i) * 64 + (col - 512)] = f2bf(v);
          else out_vt[((size_t)b * 64 + (col - 576)) * LPAD + (78 + i)] = f2bf(v);
        } else {
          out_proj[(size_t)row * 512 + col] = v;
        }
      }
}

// ---------------- flash attention: 4 waves = 4 heads, 32 q-rows, LDS K/V ----
// exp2-domain NO-MAX softmax: logits bounded (|q|,|k| ~ LN scale) so exp2(S)
// stays in f32 range; no row-max, no rescale, no in-loop cross-lane shuffles.
// l accumulates per-lane partials, reduced once at the end.
// K tile [64j][64d], V^T tile [64d][64j] staged via global_load_lds with
// source-side XOR swizzle (granule16 col ^= row&7); LDS linear; reads apply
// the same XOR. One barrier per tile (drains prefetch vmcnt + buffer reuse).
__global__ __launch_bounds__(256, 2) void k_attn(
    const unsigned short* __restrict__ q, const unsigned short* __restrict__ kbuf,
    const unsigned short* __restrict__ vt, unsigned short* __restrict__ aout) {
  int it = blockIdx.x, hh = blockIdx.y, b = blockIdx.z;
  int i0 = it * 32;
  int t = threadIdx.x;
  int w = t >> 6, lane = t & 63;
  int G = lane >> 4, li = lane & 15, li7 = lane & 7;
  int h = hh * 4 + w;

  __shared__ __align__(16) unsigned short Kl[2][4096];
  __shared__ __align__(16) unsigned short Vl[2][4096];

  int r1 = t >> 3;
  int c1 = ((t & 7) ^ (r1 & 7)) * 8;

  const unsigned short* kbase = kbuf + (size_t)b * LPAD * 64;
  const unsigned short* vbase = vt + (size_t)b * 64 * LPAD;

  bf16x8 qf[2][2];
#pragma unroll
  for (int fi = 0; fi < 2; fi++)
#pragma unroll
    for (int ks = 0; ks < 2; ks++)
      qf[fi][ks] = *reinterpret_cast<const bf16x8*>(
          q + (size_t)(b * NSEQ + i0 + fi * 16 + li) * CDIM + h * 64 + ks * 32 + G * 8);

  // stage tile 0
  stage16(kbase + (size_t)r1 * 64 + c1, &Kl[0][w * 512]);
  stage16(kbase + (size_t)(r1 + 32) * 64 + c1, &Kl[0][2048 + w * 512]);
  stage16(vbase + (size_t)r1 * LPAD + c1, &Vl[0][w * 512]);
  stage16(vbase + (size_t)(r1 + 32) * LPAD + c1, &Vl[0][2048 + w * 512]);

  f32x4 zero = {0.f, 0.f, 0.f, 0.f};
  f32x4 OT[4][2];  // [fd][fi]; row d = fd*16+G*4+r, col i = fi*16+li
#pragma unroll
  for (int fd = 0; fd < 4; fd++)
#pragma unroll
    for (int fi = 0; fi < 2; fi++) OT[fd][fi] = zero;
  float l_[2] = {0.f, 0.f};  // per-lane partial (this G's 16 j's), reduced at end

  __syncthreads();

  for (int jt = 0; jt < 38; jt++) {
    int cur = jt & 1, nxt = cur ^ 1;
    int j0 = jt * 64;
    if (jt < 37) {
      int j1 = j0 + 64;
      stage16(kbase + (size_t)(j1 + r1) * 64 + c1, &Kl[nxt][w * 512]);
      stage16(kbase + (size_t)(j1 + r1 + 32) * 64 + c1, &Kl[nxt][2048 + w * 512]);
      stage16(vbase + (size_t)r1 * LPAD + j1 + c1, &Vl[nxt][w * 512]);
      stage16(vbase + (size_t)(r1 + 32) * LPAD + j1 + c1, &Vl[nxt][2048 + w * 512]);
    }
    const char* Kc = (const char*)Kl[cur];
    const char* Vc = (const char*)Vl[cur];

    f32x4 S[4][2];
#pragma unroll
    for (int fj = 0; fj < 4; fj++) { S[fj][0] = zero; S[fj][1] = zero; }
#pragma unroll
    for (int ks = 0; ks < 2; ks++) {
      bf16x8 kf[4];
#pragma unroll
      for (int fj = 0; fj < 4; fj++)
        kf[fj] = *reinterpret_cast<const bf16x8*>(
            Kc + ((((fj * 16 + li) * 8) + ((ks * 4 + G) ^ li7)) << 4));
#pragma unroll
      for (int fj = 0; fj < 4; fj++)
#pragma unroll
        for (int fi = 0; fi < 2; fi++)
          S[fj][fi] = MFMA(kf[fj], qf[fi][ks], S[fj][fi]);
    }
    if (j0 + 64 > LKV) {
#pragma unroll
      for (int fj = 0; fj < 4; fj++)
#pragma unroll
        for (int r = 0; r < 4; r++) {
          int jg = j0 + fj * 16 + G * 4 + r;
          if (jg >= LKV) { S[fj][0][r] = -1e30f; S[fj][1][r] = -1e30f; }
        }
    }
    // no-max softmax: e = exp2(S), accumulate per-lane l, pack to bf16
    bf16x8 pf[2][2];
#pragma unroll
    for (int fi = 0; fi < 2; fi++) {
      float e[4][4];
#pragma unroll
      for (int fj = 0; fj < 4; fj++)
#pragma unroll
        for (int r = 0; r < 4; r++) e[fj][r] = __builtin_exp2f(S[fj][fi][r]);
      float s0 = (e[0][0] + e[0][1]) + (e[0][2] + e[0][3]);
      float s1 = (e[1][0] + e[1][1]) + (e[1][2] + e[1][3]);
      float s2 = (e[2][0] + e[2][1]) + (e[2][2] + e[2][3]);
      float s3 = (e[3][0] + e[3][1]) + (e[3][2] + e[3][3]);
      l_[fi] += (s0 + s1) + (s2 + s3);
#pragma unroll
      for (int ks = 0; ks < 2; ks++) {
        union { unsigned int w4[4]; bf16x8 v; } u;
        u.w4[0] = cvtpk(e[2 * ks][0], e[2 * ks][1]);
        u.w4[1] = cvtpk(e[2 * ks][2], e[2 * ks][3]);
        u.w4[2] = cvtpk(e[2 * ks + 1][0], e[2 * ks + 1][1]);
        u.w4[3] = cvtpk(e[2 * ks + 1][2], e[2 * ks + 1][3]);
        pf[fi][ks] = u.v;
      }
    }
    // PV from LDS V^T
#pragma unroll
    for (int ks = 0; ks < 2; ks++) {
#pragma unroll
      for (int fd = 0; fd < 4; fd++) {
        const char* vr = Vc + (size_t)(fd * 16 + li) * 128 + ((G & 1) << 3);
        union { unsigned short s[8]; uint2 u2[2]; bf16x8 v; } uv;
        uv.u2[0] = *reinterpret_cast<const uint2*>(vr + ((((ks * 4) + (G >> 1)) ^ li7) << 4));
        uv.u2[1] = *reinterpret_cast<const uint2*>(vr + ((((ks * 4) + (G >> 1) + 2) ^ li7) << 4));
#pragma unroll
        for (int fi = 0; fi < 2; fi++) OT[fd][fi] = MFMA(uv.v, pf[fi][ks], OT[fd][fi]);
      }
    }
    __syncthreads();
  }

  // reduce l across the 4 G replicas (first shuffles of the whole loop)
#pragma unroll
  for (int fi = 0; fi < 2; fi++) {
    l_[fi] += __shfl_xor(l_[fi], 16);
    l_[fi] += __shfl_xor(l_[fi], 32);
    float inv = 1.0f / l_[fi];
#pragma unroll
    for (int fd = 0; fd < 4; fd++) {
      union { unsigned int w2[2]; uint2 u2; } pk;
      pk.w2[0] = cvtpk(OT[fd][fi][0] * inv, OT[fd][fi][1] * inv);
      pk.w2[1] = cvtpk(OT[fd][fi][2] * inv, OT[fd][fi][3] * inv);
      *reinterpret_cast<uint2*>(
          aout + (size_t)(b * NSEQ + i0 + fi * 16 + li) * CDIM + h * 64 + fd * 16 + G * 4) =
          pk.u2;
    }
  }
}

// ---------------- per-row LN stats of proj (coalesced) ----------------
__global__ void k_stats(const float* __restrict__ proj, float* __restrict__ musig) {
  int w = threadIdx.x >> 6, lane = threadIdx.x & 63;
  int row = blockIdx.x * 4 + w;
  const float* pr = proj + (size_t)row * CDIM;
  const float4* p4 = reinterpret_cast<const float4*>(pr + lane * 8);
  float4 a = p4[0], bq = p4[1];
  float s = a.x + a.y + a.z + a.w + bq.x + bq.y + bq.z + bq.w;
  float s2 = a.x * a.x + a.y * a.y + a.z * a.z + a.w * a.w +
             bq.x * bq.x + bq.y * bq.y + bq.z * bq.z + bq.w * bq.w;
  for (int o = 32; o; o >>= 1) { s += __shfl_xor(s, o); s2 += __shfl_xor(s2, o); }
  if (lane == 0) {
    float mu = s * (1.0f / 512.0f);
    float var = s2 * (1.0f / 512.0f) - mu * mu;
    musig[row] = mu;
    musig[4 * NSEQ + row] = rsqrtf(var + 1e-5f);
  }
}

// ---------------- final LN + residual, LDS-transposed, fully coalesced ------
__global__ void k_final2(const float* __restrict__ proj, const float* __restrict__ musig,
                         const float* __restrict__ g, const float* __restrict__ x,
                         float* __restrict__ y) {
  int i0 = blockIdx.x * 32, c0 = blockIdx.y * 64, b = blockIdx.z;
  int t = threadIdx.x;
  __shared__ float lds[32][65];
  {
    int il = t >> 3, cB = (t & 7) * 8;
    const float4* src = reinterpret_cast<const float4*>(
        proj + (size_t)(b * NSEQ + i0 + il) * CDIM + c0 + cB);
    float4 v0 = src[0], v1 = src[1];
    *reinterpret_cast<float4*>(&lds[il][cB]) = v0;
    *reinterpret_cast<float4*>(&lds[il][cB + 4]) = v1;
  }
  __syncthreads();
  int ii = t & 31, cg = t >> 5;
  float mu = musig[b * NSEQ + i0 + ii];
  float rs = musig[4 * NSEQ + b * NSEQ + i0 + ii];
  const float* xb = x + (size_t)b * CDIM * NSEQ;
  float* yb = y + (size_t)b * CDIM * NSEQ;
#pragma unroll
  for (int cc = 0; cc < 8; cc++) {
    int cl = cg * 8 + cc;
    int c = c0 + cl;
    float v = lds[ii][cl];
    yb[(size_t)c * NSEQ + i0 + ii] = xb[(size_t)c * NSEQ + i0 + ii] + (v - mu) * rs * g[c];
  }
}

extern "C" void kernel_launch(void* const* d_in, const int* in_sizes, int n_in,
                              void* d_out, int out_size, void* d_ws, size_t ws_size,
                              hipStream_t stream) {
  const float* x       = (const float*)d_in[0];
  const float* context = (const float*)d_in[1];
  const float* ngamma  = (const float*)d_in[2];
  const float* null_kv = (const float*)d_in[3];
  const float* Wq      = (const float*)d_in[4];
  const float* Wkv     = (const float*)d_in[5];
  const float* clng    = (const float*)d_in[6];
  const float* clnb    = (const float*)d_in[7];
  const float* Wctx    = (const float*)d_in[8];
  const float* bctx    = (const float*)d_in[9];
  const float* Wout    = (const float*)d_in[10];
  const float* olng    = (const float*)d_in[11];
  float* y = (float*)d_out;
  char* ws = (char*)d_ws;

  unsigned short* xn    = (unsigned short*)(ws);              // 9437184 B
  unsigned short* qb    = (unsigned short*)(ws + 9437184);    // 9437184 B
  float* proj           = (float*)(ws);                       // aliases xn+qb (dead by then)
  unsigned short* aoutb = (unsigned short*)(ws + 18874368);   // 9437184 B
  float* musig          = (float*)(ws + 18874368);            // aliases aoutb (dead after gemm1)
  unsigned short* kb    = (unsigned short*)(ws + 28311552);   // 1245184 B
  unsigned short* vtb   = (unsigned short*)(ws + 29556736);   // 1245184 B
  unsigned short* WqT   = (unsigned short*)(ws + 30801920);   // 524288 B
  unsigned short* WkvT  = (unsigned short*)(ws + 31326208);   // 131072 B
  unsigned short* WctxT = (unsigned short*)(ws + 31457280);   // 196608 B
  unsigned short* WoutT = (unsigned short*)(ws + 31653888);   // 524288 B

  k_prep<<<dim3(2688), dim3(256), 0, stream>>>(Wq, Wkv, Wctx, Wout, WqT, WkvT, WctxT, WoutT);
  k_ln1<<<dim3(72, 4), dim3(256), 0, stream>>>(x, ngamma, xn);
  k_ctx<<<dim3(128, 4), dim3(128), 0, stream>>>(context, clng, clnb, WctxT, bctx, null_kv, kb, vtb);
  k_gemm<0><<<dim3(72, 5), dim3(256), 0, stream>>>(xn, WqT, WkvT, qb, kb, vtb, nullptr);
  k_attn<<<dim3(72, 2, 4), dim3(256), 0, stream>>>(qb, kb, vtb, aoutb);
  k_gemm<1><<<dim3(72, 4), dim3(256), 0, stream>>>(aoutb, WoutT, nullptr, nullptr, nullptr, nullptr, proj);
  k_stats<<<dim3(2304), dim3(256), 0, stream>>>(proj, musig);
  k_final2<<<dim3(72, 8, 4), dim3(256), 0, stream>>>(proj, musig, olng, x, y);
}

// Round 9
// 193.476 us; speedup vs baseline: 1.1845x; 1.1845x over previous
//
#include <hip/hip_runtime.h>

typedef __attribute__((ext_vector_type(8))) short bf16x8;
typedef __attribute__((ext_vector_type(4))) float f32x4;

#define LPAD 2432
#define LKV  2382
#define NSEQ 2304
#define CDIM 512
#define LPROWS (4 * NSEQ * 8)  // l-partial entries per split

__device__ __forceinline__ unsigned short f2bf(float f) {
  unsigned int u = __builtin_bit_cast(unsigned int, f);
  u += 0x7fffu + ((u >> 16) & 1u);
  return (unsigned short)(u >> 16);
}
__device__ __forceinline__ float bf2f(unsigned short s) {
  unsigned int u = ((unsigned int)s) << 16;
  return __builtin_bit_cast(float, u);
}
__device__ __forceinline__ f32x4 MFMA(bf16x8 a, bf16x8 b, f32x4 c) {
  return __builtin_amdgcn_mfma_f32_16x16x32_bf16(a, b, c, 0, 0, 0);
}
__device__ __forceinline__ void stage16(const unsigned short* g, unsigned short* l) {
  __builtin_amdgcn_global_load_lds((const __attribute__((address_space(1))) void*)g,
                                   (__attribute__((address_space(3))) void*)l, 16, 0, 0);
}
__device__ __forceinline__ unsigned int cvtpk(float a, float b) {
  unsigned int r;
  asm("v_cvt_pk_bf16_f32 %0, %1, %2" : "=v"(r) : "v"(a), "v"(b));
  return r;
}
// interleaved V^T column position within each 32-chunk
__device__ __forceinline__ int Fj(int j) {
  return (j & ~31) | ((j & 15) << 1) | ((j >> 4) & 1);
}

// ---------------- weight transpose + bf16 convert ----------------
__global__ void k_prep(const float* __restrict__ Wq, const float* __restrict__ Wkv,
                       const float* __restrict__ Wctx, const float* __restrict__ Wout,
                       unsigned short* __restrict__ WqT, unsigned short* __restrict__ WkvT,
                       unsigned short* __restrict__ WctxT, unsigned short* __restrict__ WoutT) {
  int idx = blockIdx.x * 256 + threadIdx.x;
  if (idx < 262144) {
    int n = idx >> 9, k = idx & 511;
    WqT[idx] = f2bf(Wq[k * 512 + n]);
  } else if ((idx -= 262144) < 65536) {
    int n = idx >> 9, k = idx & 511;
    WkvT[idx] = f2bf(Wkv[k * 128 + n]);
  } else if ((idx -= 65536) < 98304) {
    int n = idx / 768, k = idx - n * 768;
    WctxT[idx] = f2bf(Wctx[k * 128 + n]);
  } else {
    idx -= 98304;
    int n = idx >> 9, k = idx & 511;
    WoutT[idx] = f2bf(Wout[k * 512 + n]);
  }
}

// ---------------- LN over C of x (B,C,N) -> xn bf16 (B*N, C) ----------------
__global__ void k_ln1(const float* __restrict__ x, const float* __restrict__ g,
                      unsigned short* __restrict__ xn) {
  int b = blockIdx.y;
  int i0 = blockIdx.x * 32;
  int t = threadIdx.x;
  int ii = t & 31, ci = t >> 5;
  const float* xb = x + (size_t)b * CDIM * NSEQ;
  float s = 0.f, s2 = 0.f;
  for (int c = ci; c < CDIM; c += 8) {
    float v = xb[(size_t)c * NSEQ + i0 + ii];
    s += v; s2 += v * v;
  }
  __shared__ float ls[8][32], ls2[8][32];
  __shared__ float lmu[32], lrs[32];
  ls[ci][ii] = s; ls2[ci][ii] = s2;
  __syncthreads();
  if (t < 32) {
    float a = 0.f, a2 = 0.f;
    for (int q = 0; q < 8; q++) { a += ls[q][t]; a2 += ls2[q][t]; }
    float mu = a * (1.0f / 512.0f);
    float var = a2 * (1.0f / 512.0f) - mu * mu;
    lmu[t] = mu; lrs[t] = rsqrtf(var + 1e-5f);
  }
  __syncthreads();
  float mu = lmu[ii], rs = lrs[ii];
  unsigned short* xrow = xn + (size_t)(b * NSEQ + i0 + ii) * CDIM;
  for (int c = ci; c < CDIM; c += 8) {
    float v = xb[(size_t)c * NSEQ + i0 + ii];
    xrow[c] = f2bf((v - mu) * rs * g[c]);
  }
}

// ---------------- context LN + projection; null row + zero pads ----------
__global__ void k_ctx(const float* __restrict__ ctx, const float* __restrict__ g,
                      const float* __restrict__ be, const unsigned short* __restrict__ WctxT,
                      const float* __restrict__ bctx, const float* __restrict__ null_kv,
                      unsigned short* __restrict__ kb, unsigned short* __restrict__ vt) {
  int b = blockIdx.y, j = blockIdx.x;
  int t = threadIdx.x;
  if (j == 77) {
    if (t < 64) kb[((size_t)b * LPAD + 77) * 64 + t] = f2bf(null_kv[t]);
    else vt[((size_t)b * 64 + (t - 64)) * LPAD + Fj(77)] = f2bf(null_kv[64 + (t - 64)]);
    return;
  }
  if (j > 77) {
    int jj = LKV + (j - 78);
    if (t < 64) kb[((size_t)b * LPAD + jj) * 64 + t] = 0;
    else vt[((size_t)b * 64 + (t - 64)) * LPAD + Fj(jj)] = 0;
    return;
  }
  __shared__ float row[768];
  __shared__ float red[4];
  const float* src = ctx + (size_t)(b * 77 + j) * 768;
  float s = 0.f, s2 = 0.f;
  for (int k = t; k < 768; k += 128) {
    float v = src[k];
    row[k] = v; s += v; s2 += v * v;
  }
  for (int o = 32; o; o >>= 1) { s += __shfl_xor(s, o); s2 += __shfl_xor(s2, o); }
  if ((t & 63) == 0) { red[(t >> 6) * 2] = s; red[(t >> 6) * 2 + 1] = s2; }
  __syncthreads();
  float S = red[0] + red[2], S2 = red[1] + red[3];
  float mu = S * (1.0f / 768.0f);
  float rs = rsqrtf(S2 * (1.0f / 768.0f) - mu * mu + 1e-5f);
  __syncthreads();
  for (int k = t; k < 768; k += 128) row[k] = (row[k] - mu) * rs * g[k] + be[k];
  __syncthreads();
  const uint4* w4 = reinterpret_cast<const uint4*>(WctxT + (size_t)t * 768);
  float acc = 0.f;
  for (int k8 = 0; k8 < 96; k8++) {
    union { uint4 u; unsigned short s[8]; } wv;
    wv.u = w4[k8];
#pragma unroll
    for (int e = 0; e < 8; e++) acc += row[k8 * 8 + e] * bf2f(wv.s[e]);
  }
  acc += bctx[t];
  if (t < 64) kb[((size_t)b * LPAD + j) * 64 + t] = f2bf(acc);
  else vt[((size_t)b * 64 + (t - 64)) * LPAD + Fj(j)] = f2bf(acc);
}

// ---------------- MFMA GEMM ----------------
template <int MODE>
__global__ __launch_bounds__(256, 1) void k_gemm(
    const unsigned short* __restrict__ A, const unsigned short* __restrict__ BT0,
    const unsigned short* __restrict__ BT1, unsigned short* __restrict__ out_q,
    unsigned short* __restrict__ out_k, unsigned short* __restrict__ out_vt,
    float* __restrict__ out_proj) {
  int m0 = blockIdx.x * 128, n0 = blockIdx.y * 128;
  int t = threadIdx.x;
  int lane = t & 63, w = t >> 6;
  int wm = w >> 1, wn = w & 1;
  int G = lane >> 4, li = lane & 15;
  __shared__ unsigned short Al[128][72];
  __shared__ unsigned short Bl[128][72];
  const unsigned short* BT = (MODE == 0 && n0 >= 512) ? BT1 : BT0;
  int bn0 = (MODE == 0 && n0 >= 512) ? n0 - 512 : n0;
  f32x4 zero = {0.f, 0.f, 0.f, 0.f};
  f32x4 acc[4][4];
#pragma unroll
  for (int a = 0; a < 4; a++)
#pragma unroll
    for (int c = 0; c < 4; c++) acc[a][c] = zero;
  int sr = t >> 1, sc = (t & 1) * 32;
  for (int k0 = 0; k0 < 512; k0 += 64) {
    const uint4* sA = reinterpret_cast<const uint4*>(A + (size_t)(m0 + sr) * 512 + k0 + sc);
    const uint4* sB = reinterpret_cast<const uint4*>(BT + (size_t)(bn0 + sr) * 512 + k0 + sc);
    uint4 a0 = sA[0], a1 = sA[1], a2 = sA[2], a3 = sA[3];
    uint4 b0 = sB[0], b1 = sB[1], b2 = sB[2], b3 = sB[3];
    uint4* dA = reinterpret_cast<uint4*>(&Al[sr][sc]);
    uint4* dB = reinterpret_cast<uint4*>(&Bl[sr][sc]);
    dA[0] = a0; dA[1] = a1; dA[2] = a2; dA[3] = a3;
    dB[0] = b0; dB[1] = b1; dB[2] = b2; dB[3] = b3;
    __syncthreads();
#pragma unroll
    for (int ks = 0; ks < 2; ks++) {
      bf16x8 af[4], bfr[4];
#pragma unroll
      for (int f = 0; f < 4; f++) {
        af[f] = *reinterpret_cast<const bf16x8*>(&Al[wm * 64 + f * 16 + li][ks * 32 + G * 8]);
        bfr[f] = *reinterpret_cast<const bf16x8*>(&Bl[wn * 64 + f * 16 + li][ks * 32 + G * 8]);
      }
#pragma unroll
      for (int fm = 0; fm < 4; fm++)
#pragma unroll
        for (int fn = 0; fn < 4; fn++)
          acc[fm][fn] = MFMA(af[fm], bfr[fn], acc[fm][fn]);
    }
    __syncthreads();
  }
#pragma unroll
  for (int fm = 0; fm < 4; fm++)
#pragma unroll
    for (int fn = 0; fn < 4; fn++)
#pragma unroll
      for (int r = 0; r < 4; r++) {
        int row = m0 + wm * 64 + fm * 16 + G * 4 + r;
        int col = n0 + wn * 64 + fn * 16 + li;
        float v = acc[fm][fn][r];
        if (MODE == 0) {
          int b = row / NSEQ, i = row - b * NSEQ;
          // q pre-scaled by 1/sqrt(dh) * log2(e): softmax runs in exp2 domain
          if (col < 512) out_q[(size_t)row * 512 + col] = f2bf(v * 0.18033688011112042f);
          else if (col < 576) out_k[((size_t)b * LPAD + 78 + i) * 64 + (col - 512)] = f2bf(v);
          else out_vt[((size_t)b * 64 + (col - 576)) * LPAD + Fj(78 + i)] = f2bf(v);
        } else {
          out_proj[(size_t)row * 512 + col] = v;
        }
      }
}

// ---------------- flash attention: 2-way KV split, 4 waves = 4 heads --------
// no-max exp2 softmax -> split partials combine by pure addition.
// K tile [64j][64d]; V^T tile [64d][64 interleaved-j] (Fj layout) staged via
// global_load_lds with source-side XOR swizzle; reads apply same XOR.
// Double-buffer parity is LOCAL (u&1): split 1 starts at jt=19 (odd) and must
// still read buffer [0] first (R8 bug: used global jt parity -> uninit LDS).
__global__ __launch_bounds__(256, 2) void k_attn(
    const unsigned short* __restrict__ q, const unsigned short* __restrict__ kbuf,
    const unsigned short* __restrict__ vt, unsigned short* __restrict__ pO0,
    unsigned short* __restrict__ pO1, float* __restrict__ lp) {
  int bx = blockIdx.x;
  int it = bx >> 1, sp = bx & 1;
  int hh = blockIdx.y, b = blockIdx.z;
  int i0 = it * 32;
  int t = threadIdx.x;
  int w = t >> 6, lane = t & 63;
  int G = lane >> 4, li = lane & 15, li7 = lane & 7;
  int h = hh * 4 + w;

  __shared__ __align__(16) unsigned short Kl[2][4096];
  __shared__ __align__(16) unsigned short Vl[2][4096];

  int r1 = t >> 3;
  int c1 = ((t & 7) ^ (r1 & 7)) * 8;

  const unsigned short* kbase = kbuf + (size_t)b * LPAD * 64;
  const unsigned short* vbase = vt + (size_t)b * 64 * LPAD;

  bf16x8 qf[2][2];
#pragma unroll
  for (int fi = 0; fi < 2; fi++)
#pragma unroll
    for (int ks = 0; ks < 2; ks++)
      qf[fi][ks] = *reinterpret_cast<const bf16x8*>(
          q + (size_t)(b * NSEQ + i0 + fi * 16 + li) * CDIM + h * 64 + ks * 32 + G * 8);

  int jt0 = sp * 19;

  // stage first tile of this split into buffer [0]
  {
    int j0 = jt0 * 64;
    stage16(kbase + (size_t)(j0 + r1) * 64 + c1, &Kl[0][w * 512]);
    stage16(kbase + (size_t)(j0 + r1 + 32) * 64 + c1, &Kl[0][2048 + w * 512]);
    stage16(vbase + (size_t)r1 * LPAD + j0 + c1, &Vl[0][w * 512]);
    stage16(vbase + (size_t)(r1 + 32) * LPAD + j0 + c1, &Vl[0][2048 + w * 512]);
  }

  f32x4 zero = {0.f, 0.f, 0.f, 0.f};
  f32x4 OT[4][2];  // [fd][fi]; row d = fd*16+G*4+r, col i = fi*16+li
#pragma unroll
  for (int fd = 0; fd < 4; fd++)
#pragma unroll
    for (int fi = 0; fi < 2; fi++) OT[fd][fi] = zero;
  float l_[2] = {0.f, 0.f};

  __syncthreads();

  for (int u = 0; u < 19; u++) {
    int jt = jt0 + u;
    int cur = u & 1, nxt = cur ^ 1;  // LOCAL parity
    int j0 = jt * 64;
    if (u + 1 < 19) {
      int j1 = j0 + 64;
      stage16(kbase + (size_t)(j1 + r1) * 64 + c1, &Kl[nxt][w * 512]);
      stage16(kbase + (size_t)(j1 + r1 + 32) * 64 + c1, &Kl[nxt][2048 + w * 512]);
      stage16(vbase + (size_t)r1 * LPAD + j1 + c1, &Vl[nxt][w * 512]);
      stage16(vbase + (size_t)(r1 + 32) * LPAD + j1 + c1, &Vl[nxt][2048 + w * 512]);
    }
    const char* Kc = (const char*)Kl[cur];
    const char* Vc = (const char*)Vl[cur];

    f32x4 S[4][2];
#pragma unroll
    for (int fj = 0; fj < 4; fj++) { S[fj][0] = zero; S[fj][1] = zero; }
#pragma unroll
    for (int ks = 0; ks < 2; ks++) {
      bf16x8 kf[4];
#pragma unroll
      for (int fj = 0; fj < 4; fj++)
        kf[fj] = *reinterpret_cast<const bf16x8*>(
            Kc + ((((fj * 16 + li) * 8) + ((ks * 4 + G) ^ li7)) << 4));
#pragma unroll
      for (int fj = 0; fj < 4; fj++)
#pragma unroll
        for (int fi = 0; fi < 2; fi++)
          S[fj][fi] = MFMA(kf[fj], qf[fi][ks], S[fj][fi]);
    }
    if (j0 + 64 > LKV) {
#pragma unroll
      for (int fj = 0; fj < 4; fj++)
#pragma unroll
        for (int r = 0; r < 4; r++) {
          int jg = j0 + fj * 16 + G * 4 + r;
          if (jg >= LKV) { S[fj][0][r] = -1e30f; S[fj][1][r] = -1e30f; }
        }
    }
    // no-max softmax: e = exp2(S); pack pf in interleaved-j bijection:
    // B k-slot (G,E) <-> j = ks*32 + (E&1)*16 + G*4 + (E>>1)
    bf16x8 pf[2][2];
#pragma unroll
    for (int fi = 0; fi < 2; fi++) {
      float e[4][4];
#pragma unroll
      for (int fj = 0; fj < 4; fj++)
#pragma unroll
        for (int r = 0; r < 4; r++) e[fj][r] = __builtin_exp2f(S[fj][fi][r]);
      float s0 = (e[0][0] + e[0][1]) + (e[0][2] + e[0][3]);
      float s1 = (e[1][0] + e[1][1]) + (e[1][2] + e[1][3]);
      float s2 = (e[2][0] + e[2][1]) + (e[2][2] + e[2][3]);
      float s3 = (e[3][0] + e[3][1]) + (e[3][2] + e[3][3]);
      l_[fi] += (s0 + s1) + (s2 + s3);
#pragma unroll
      for (int ks = 0; ks < 2; ks++) {
        union { unsigned int w4[4]; bf16x8 v; } u2;
#pragma unroll
        for (int m = 0; m < 4; m++) u2.w4[m] = cvtpk(e[2 * ks][m], e[2 * ks + 1][m]);
        pf[fi][ks] = u2.v;
      }
    }
    // PV from LDS V^T (interleaved layout): one b128 per (ks, fd)
#pragma unroll
    for (int ks = 0; ks < 2; ks++) {
#pragma unroll
      for (int fd = 0; fd < 4; fd++) {
        bf16x8 uv = *reinterpret_cast<const bf16x8*>(
            Vc + (((fd * 16 + li) * 8 + ((ks * 4 + G) ^ li7)) << 4));
#pragma unroll
        for (int fi = 0; fi < 2; fi++) OT[fd][fi] = MFMA(uv, pf[fi][ks], OT[fd][fi]);
      }
    }
    __syncthreads();
  }

  // write unnormalized partials + l partials
  unsigned short* pO = sp ? pO1 : pO0;
#pragma unroll
  for (int fi = 0; fi < 2; fi++) {
    l_[fi] += __shfl_xor(l_[fi], 16);
    l_[fi] += __shfl_xor(l_[fi], 32);
    int row = b * NSEQ + i0 + fi * 16 + li;
    if (G == 0) lp[sp * LPROWS + row * 8 + h] = l_[fi];
#pragma unroll
    for (int fd = 0; fd < 4; fd++) {
      union { unsigned int w2[2]; uint2 u2; } pk;
      pk.w2[0] = cvtpk(OT[fd][fi][0], OT[fd][fi][1]);
      pk.w2[1] = cvtpk(OT[fd][fi][2], OT[fd][fi][3]);
      *reinterpret_cast<uint2*>(pO + (size_t)row * CDIM + h * 64 + fd * 16 + G * 4) = pk.u2;
    }
  }
}

// ---------------- merge the two KV-split partials ----------------
// out (in place over pO0) = (O0 + O1) / (l0 + l1), bf16
__global__ void k_merge(unsigned short* __restrict__ pO0,
                        const unsigned short* __restrict__ pO1,
                        const float* __restrict__ lp) {
  int c = blockIdx.x * 256 + threadIdx.x;  // 16B chunk index (8 bf16)
  size_t base = (size_t)c * 8;
  int row = (int)(base >> 9);
  int h = (int)((base >> 6) & 7);
  float l = lp[row * 8 + h] + lp[LPROWS + row * 8 + h];
  float inv = 1.0f / l;
  union { uint4 u; unsigned short s[8]; } a, bq, o;
  a.u = *reinterpret_cast<const uint4*>(pO0 + base);
  bq.u = *reinterpret_cast<const uint4*>(pO1 + base);
  unsigned int* ow = reinterpret_cast<unsigned int*>(&o.u);
#pragma unroll
  for (int m = 0; m < 4; m++) {
    float v0 = (bf2f(a.s[2 * m]) + bf2f(bq.s[2 * m])) * inv;
    float v1 = (bf2f(a.s[2 * m + 1]) + bf2f(bq.s[2 * m + 1])) * inv;
    ow[m] = cvtpk(v0, v1);
  }
  *reinterpret_cast<uint4*>(pO0 + base) = o.u;
}

// ---------------- per-row LN stats of proj (coalesced) ----------------
__global__ void k_stats(const float* __restrict__ proj, float* __restrict__ musig) {
  int w = threadIdx.x >> 6, lane = threadIdx.x & 63;
  int row = blockIdx.x * 4 + w;
  const float* pr = proj + (size_t)row * CDIM;
  const float4* p4 = reinterpret_cast<const float4*>(pr + lane * 8);
  float4 a = p4[0], bq = p4[1];
  float s = a.x + a.y + a.z + a.w + bq.x + bq.y + bq.z + bq.w;
  float s2 = a.x * a.x + a.y * a.y + a.z * a.z + a.w * a.w +
             bq.x * bq.x + bq.y * bq.y + bq.z * bq.z + bq.w * bq.w;
  for (int o = 32; o; o >>= 1) { s += __shfl_xor(s, o); s2 += __shfl_xor(s2, o); }
  if (lane == 0) {
    float mu = s * (1.0f / 512.0f);
    float var = s2 * (1.0f / 512.0f) - mu * mu;
    musig[row] = mu;
    musig[4 * NSEQ + row] = rsqrtf(var + 1e-5f);
  }
}

// ---------------- final LN + residual, LDS-transposed, fully coalesced ------
__global__ void k_final2(const float* __restrict__ proj, const float* __restrict__ musig,
                         const float* __restrict__ g, const float* __restrict__ x,
                         float* __restrict__ y) {
  int i0 = blockIdx.x * 32, c0 = blockIdx.y * 64, b = blockIdx.z;
  int t = threadIdx.x;
  __shared__ float lds[32][65];
  {
    int il = t >> 3, cB = (t & 7) * 8;
    const float4* src = reinterpret_cast<const float4*>(
        proj + (size_t)(b * NSEQ + i0 + il) * CDIM + c0 + cB);
    float4 v0 = src[0], v1 = src[1];
    *reinterpret_cast<float4*>(&lds[il][cB]) = v0;
    *reinterpret_cast<float4*>(&lds[il][cB + 4]) = v1;
  }
  __syncthreads();
  int ii = t & 31, cg = t >> 5;
  float mu = musig[b * NSEQ + i0 + ii];
  float rs = musig[4 * NSEQ + b * NSEQ + i0 + ii];
  const float* xb = x + (size_t)b * CDIM * NSEQ;
  float* yb = y + (size_t)b * CDIM * NSEQ;
#pragma unroll
  for (int cc = 0; cc < 8; cc++) {
    int cl = cg * 8 + cc;
    int c = c0 + cl;
    float v = lds[ii][cl];
    yb[(size_t)c * NSEQ + i0 + ii] = xb[(size_t)c * NSEQ + i0 + ii] + (v - mu) * rs * g[c];
  }
}

extern "C" void kernel_launch(void* const* d_in, const int* in_sizes, int n_in,
                              void* d_out, int out_size, void* d_ws, size_t ws_size,
                              hipStream_t stream) {
  const float* x       = (const float*)d_in[0];
  const float* context = (const float*)d_in[1];
  const float* ngamma  = (const float*)d_in[2];
  const float* null_kv = (const float*)d_in[3];
  const float* Wq      = (const float*)d_in[4];
  const float* Wkv     = (const float*)d_in[5];
  const float* clng    = (const float*)d_in[6];
  const float* clnb    = (const float*)d_in[7];
  const float* Wctx    = (const float*)d_in[8];
  const float* bctx    = (const float*)d_in[9];
  const float* Wout    = (const float*)d_in[10];
  const float* olng    = (const float*)d_in[11];
  float* y = (float*)d_out;
  char* ws = (char*)d_ws;

  unsigned short* xn    = (unsigned short*)(ws);              // 9437184 B (also pO1 during attn)
  unsigned short* qb    = (unsigned short*)(ws + 9437184);    // 9437184 B
  float* proj           = (float*)(ws);                       // aliases xn+qb (dead by then)
  unsigned short* aoutb = (unsigned short*)(ws + 18874368);   // 9437184 B (pO0 -> merged)
  float* musig          = (float*)(ws + 18874368);            // aliases aoutb (dead after gemm1)
  unsigned short* kb    = (unsigned short*)(ws + 28311552);   // 1245184 B
  unsigned short* vtb   = (unsigned short*)(ws + 29556736);   // 1245184 B
  unsigned short* WqT   = (unsigned short*)(ws + 30801920);   // 524288 B
  unsigned short* WkvT  = (unsigned short*)(ws + 31326208);   // 131072 B
  unsigned short* WctxT = (unsigned short*)(ws + 31457280);   // 196608 B
  unsigned short* WoutT = (unsigned short*)(ws + 31653888);   // 524288 B
  // l-partials (589824 B) overlay WqT+WkvT (655360 B) — dead after k_gemm<0>
  float* lpart          = (float*)(ws + 30801920);

  k_prep<<<dim3(2688), dim3(256), 0, stream>>>(Wq, Wkv, Wctx, Wout, WqT, WkvT, WctxT, WoutT);
  k_ln1<<<dim3(72, 4), dim3(256), 0, stream>>>(x, ngamma, xn);
  k_ctx<<<dim3(128, 4), dim3(128), 0, stream>>>(context, clng, clnb, WctxT, bctx, null_kv, kb, vtb);
  k_gemm<0><<<dim3(72, 5), dim3(256), 0, stream>>>(xn, WqT, WkvT, qb, kb, vtb, nullptr);
  k_attn<<<dim3(144, 2, 4), dim3(256), 0, stream>>>(qb, kb, vtb, aoutb, xn, lpart);
  k_merge<<<dim3(2304), dim3(256), 0, stream>>>(aoutb, xn, lpart);
  k_gemm<1><<<dim3(72, 4), dim3(256), 0, stream>>>(aoutb, WoutT, nullptr, nullptr, nullptr, nullptr, proj);
  k_stats<<<dim3(2304), dim3(256), 0, stream>>>(proj, musig);
  k_final2<<<dim3(72, 8, 4), dim3(256), 0, stream>>>(proj, musig, olng, x, y);
}